// Round 1
// baseline (74.950 us; speedup 1.0000x reference)
//
#include <hip/hip_runtime.h>
#include <hip/hip_bf16.h>
#include <math.h>

// Problem constants (from reference setup_inputs):
//   feature_map [B=2, H=38, W=38, C=512] float32 (NHWC, C contiguous)
//   rois        [B=2, N=64, 4] int32  (y, x, h, w), h,w >= P
//   out         [B, N, P, P, C] float32, P = 7
#define RB 2
#define RN 64
#define RH 38
#define RW 38
#define RC 512
#define RP 7

// One block per output cell (b, n, py, px). 128 threads, each owns 4
// contiguous channels via float4 -> 16 B/lane, fully coalesced along C.
// Bin pixel count is <= ceil(38/7)^2 = 36; bins partition the ROI so no
// pixel is read twice within a ROI. Feature map (5.9 MB) is L2/LLC
// resident, so reads are cache-bandwidth bound, not HBM bound.
__global__ __launch_bounds__(128) void roi_pool_kernel(
    const float* __restrict__ fm, const int* __restrict__ rois,
    float* __restrict__ out) {
  int cell = blockIdx.x;                 // ((b*RN + n)*RP + py)*RP + px
  int px = cell % RP;
  int t = cell / RP;
  int py = t % RP;
  t /= RP;
  int n = t % RN;
  int b = t / RN;

  const int* r = rois + ((b * RN + n) << 2);
  int y0 = r[0], x0 = r[1], h = r[2], w = r[3];

  // Bin [ys, ye) x [xs, xe) in ROI-relative coords; equivalent to the
  // reference's b = (P*r + P-1)//h inverse mapping.
  int ys = (py * h) / RP, ye = ((py + 1) * h) / RP;
  int xs = (px * w) / RP, xe = ((px + 1) * w) / RP;

  int tid = threadIdx.x;                 // 0..127
  int cbase = tid << 2;                  // channel offset, float4 aligned

  float4 m = make_float4(-INFINITY, -INFINITY, -INFINITY, -INFINITY);

  for (int yy = ys; yy < ye; ++yy) {
    const float* rowp =
        fm + ((size_t)((b * RH + y0 + yy) * RW + x0 + xs)) * RC + cbase;
    for (int xx = xs; xx < xe; ++xx) {
      float4 v = *(const float4*)rowp;
      m.x = fmaxf(m.x, v.x);
      m.y = fmaxf(m.y, v.y);
      m.z = fmaxf(m.z, v.z);
      m.w = fmaxf(m.w, v.w);
      rowp += RC;
    }
  }

  *(float4*)(out + (size_t)cell * RC + cbase) = m;
}

extern "C" void kernel_launch(void* const* d_in, const int* in_sizes, int n_in,
                              void* d_out, int out_size, void* d_ws, size_t ws_size,
                              hipStream_t stream) {
  const float* fm = (const float*)d_in[0];
  const int* rois = (const int*)d_in[1];
  float* out = (float*)d_out;

  int n_cells = RB * RN * RP * RP;  // 6272
  roi_pool_kernel<<<n_cells, 128, 0, stream>>>(fm, rois, out);
}

// Round 3
// 69.547 us; speedup vs baseline: 1.0777x; 1.0777x over previous
//
#include <hip/hip_runtime.h>
#include <hip/hip_bf16.h>
#include <math.h>

// Problem constants:
//   feature_map [B=2, H=38, W=38, C=512] float32 (NHWC, C contiguous)
//   rois        [B=2, N=64, 4] int32  (y, x, h, w), h,w >= P
//   out         [B, N, P, P, C] float32, P = 7
#define RB 2
#define RN 64
#define RH 38
#define RW 38
#define RC 512
#define RP 7
#define CELLS (RB * RN * RP * RP)  // 6272
#define CPI (RN * RP * RP)         // cells per image = 3136
#define PPI (CPI / 2)              // cell-pairs per image = 1568

typedef float vfloat4 __attribute__((ext_vector_type(4)));  // native vec for
                                                            // nontemporal st

// One WAVE per output cell: 64 lanes x 8 channels (2x float4) = 512 ch.
// 128-thread blocks = 2 cells/block -> 3136 blocks, 2 waves each
// (16 blocks/CU -> full 32 waves/CU occupancy).
//
// ILP: 2 independent float4 chains per pixel + prefetch-next-pixel software
// pipeline -> up to 4 loads in flight per wave (vs 1 in R0).
//
// XCD swizzle: assuming round-robin blockIdx%8 -> XCD, route image 0's cells
// to XCDs 0-3 and image 1's to XCDs 4-7. Each image is ~3 MB < 4 MB per-XCD
// L2, so reads become L2 hits instead of LLC round-trips.
__global__ __launch_bounds__(128) void roi_pool_kernel(
    const float* __restrict__ fm, const int* __restrict__ rois,
    float* __restrict__ out) {
  int wave = threadIdx.x >> 6;
  int lane = threadIdx.x & 63;

  int bx = blockIdx.x;           // [0, 3136)
  int x = bx & 7;                // presumed XCD
  int j = bx >> 3;               // [0, 392)
  int img = x >> 2;              // 0..1
  int pair = img * PPI + ((j << 2) | (x & 3));  // bijective -> [0, 3136)
  int cell = pair * 2 + wave;    // [0, 6272), layout ((b*RN+n)*RP+py)*RP+px

  int px = cell % RP;
  int t = cell / RP;
  int py = t % RP;
  t /= RP;                       // roi id = b*RN + n
  int b = t / RN;

  const int* r = rois + (t << 2);
  int y0 = r[0], x0 = r[1], h = r[2], w = r[3];

  // Bin [ys,ye) x [xs,xe); bins partition the ROI exactly (h,w >= 7).
  int ys = (py * h) / RP, ye = ((py + 1) * h) / RP;
  int xs = (px * w) / RP, xe = ((px + 1) * w) / RP;
  int bw = xe - xs;
  int cnt = bw * (ye - ys);      // >= 1

  const float4* p =
      (const float4*)(fm +
                      (size_t)((b * RH + y0 + ys) * RW + x0 + xs) * RC) +
      lane;
  const int pixstep = RC / 4;                  // 128 float4 per pixel step
  const int wrapstep = (RW - bw) * (RC / 4);   // extra step at row wrap

  float4 m0 = make_float4(-INFINITY, -INFINITY, -INFINITY, -INFINITY);
  float4 m1 = m0;

  // Software pipeline: a = current pixel (in flight), n = next pixel.
  float4 a0 = p[0];
  float4 a1 = p[64];   // +256 channels
  int xrem = bw;
  for (int k = 1; k < cnt; ++k) {
    p += pixstep;
    if (--xrem == 0) { xrem = bw; p += wrapstep; }
    float4 n0 = p[0];
    float4 n1 = p[64];
    m0.x = fmaxf(m0.x, a0.x); m0.y = fmaxf(m0.y, a0.y);
    m0.z = fmaxf(m0.z, a0.z); m0.w = fmaxf(m0.w, a0.w);
    m1.x = fmaxf(m1.x, a1.x); m1.y = fmaxf(m1.y, a1.y);
    m1.z = fmaxf(m1.z, a1.z); m1.w = fmaxf(m1.w, a1.w);
    a0 = n0; a1 = n1;
  }
  m0.x = fmaxf(m0.x, a0.x); m0.y = fmaxf(m0.y, a0.y);
  m0.z = fmaxf(m0.z, a0.z); m0.w = fmaxf(m0.w, a0.w);
  m1.x = fmaxf(m1.x, a1.x); m1.y = fmaxf(m1.y, a1.y);
  m1.z = fmaxf(m1.z, a1.z); m1.w = fmaxf(m1.w, a1.w);

  vfloat4* o = (vfloat4*)(out + (size_t)cell * RC) + lane;
  vfloat4 s0 = {m0.x, m0.y, m0.z, m0.w};
  vfloat4 s1 = {m1.x, m1.y, m1.z, m1.w};
  __builtin_nontemporal_store(s0, o);       // streaming write: don't pollute
  __builtin_nontemporal_store(s1, o + 64);  // L2 (keep it for the fm)
}

extern "C" void kernel_launch(void* const* d_in, const int* in_sizes, int n_in,
                              void* d_out, int out_size, void* d_ws, size_t ws_size,
                              hipStream_t stream) {
  const float* fm = (const float*)d_in[0];
  const int* rois = (const int*)d_in[1];
  float* out = (float*)d_out;

  roi_pool_kernel<<<CELLS / 2, 128, 0, stream>>>(fm, rois, out);
}

// Round 4
// 69.017 us; speedup vs baseline: 1.0860x; 1.0077x over previous
//
#include <hip/hip_runtime.h>
#include <hip/hip_bf16.h>
#include <math.h>

// Problem constants:
//   feature_map [B=2, H=38, W=38, C=512] float32 (NHWC, C contiguous)
//   rois        [B=2, N=64, 4] int32  (y, x, h, w), h,w >= P
//   out         [B, N, P, P, C] float32, P = 7
#define RB 2
#define RN 64
#define RH 38
#define RW 38
#define RC 512
#define RP 7
#define CELLS (RB * RN * RP * RP)  // 6272
#define CPI (RN * RP * RP)         // cells per image = 3136
#define PPI (CPI / 2)              // cell-pairs per image = 1568

typedef float vfloat4 __attribute__((ext_vector_type(4)));

// One WAVE per (cell, channel-half): 64 lanes x 4 ch (1x float4) = 256 ch.
// 256-thread blocks = 4 waves = 2 cells -> 3136 blocks, full 32-wave/CU
// occupancy (2x the waves of R3 -> 2x latency cover).
//
// Depth-4 software pipeline: 4 independent float4 loads in flight per wave,
// exposed per-pixel latency ~ lat/4. ROI dims are wave-uniform, so all
// pipeline control flow is scalar (no divergence).
//
// XCD swizzle (round-robin blockIdx%8 -> XCD assumed): image 0 -> XCDs 0-3,
// image 1 -> XCDs 4-7; each ~3 MB image fits a 4 MB per-XCD L2.
__global__ __launch_bounds__(256) void roi_pool_kernel(
    const float* __restrict__ fm, const int* __restrict__ rois,
    float* __restrict__ out) {
  int wv = threadIdx.x >> 6;     // 0..3
  int lane = threadIdx.x & 63;
  int half = wv & 1;             // channel half: 0 -> ch[0,256), 1 -> [256,512)

  int bx = blockIdx.x;           // [0, 3136)
  int x = bx & 7;                // presumed XCD
  int j = bx >> 3;               // [0, 392)
  int img = x >> 2;              // 0..1
  int pair = img * PPI + ((j << 2) | (x & 3));  // bijective -> [0, 3136)
  int cell = pair * 2 + (wv >> 1);  // [0, 6272)

  int px = cell % RP;
  int t = cell / RP;
  int py = t % RP;
  t /= RP;                       // roi id = b*RN + n
  int b = t / RN;

  const int* r = rois + (t << 2);
  int y0 = r[0], x0 = r[1], h = r[2], w = r[3];

  // Bin [ys,ye) x [xs,xe); bins partition the ROI exactly (h,w >= 7),
  // so every bin is non-empty.
  int ys = (py * h) / RP, ye = ((py + 1) * h) / RP;
  int xs = (px * w) / RP, xe = ((px + 1) * w) / RP;
  int bw = xe - xs;
  int cnt = bw * (ye - ys);      // 1..36

  const float4* p =
      (const float4*)(fm +
                      (size_t)((b * RH + y0 + ys) * RW + x0 + xs) * RC) +
      (half << 6) + lane;
  const int pixstep = RC / 4;                  // 128 float4 per pixel
  const int wrapstep = (RW - bw) * (RC / 4);   // extra step at row wrap

#define STEP() \
  { p += pixstep; if (--xrem == 0) { xrem = bw; p += wrapstep; } }

  float4 m = make_float4(-INFINITY, -INFINITY, -INFINITY, -INFINITY);
  int xrem = bw;

  // Depth-4 pipeline. All branches wave-uniform (cnt/bw uniform per wave).
  float4 a0, a1, a2, a3;
  a0 = *p;
  if (cnt > 1) { STEP(); a1 = *p; }
  if (cnt > 2) { STEP(); a2 = *p; }
  if (cnt > 3) { STEP(); a3 = *p; }
  int rem = cnt - 4;
  while (rem > 0) {
    m.x = fmaxf(m.x, a0.x); m.y = fmaxf(m.y, a0.y);
    m.z = fmaxf(m.z, a0.z); m.w = fmaxf(m.w, a0.w);
    STEP(); a0 = *p; --rem;
    if (rem > 0) {
      m.x = fmaxf(m.x, a1.x); m.y = fmaxf(m.y, a1.y);
      m.z = fmaxf(m.z, a1.z); m.w = fmaxf(m.w, a1.w);
      STEP(); a1 = *p; --rem;
    }
    if (rem > 0) {
      m.x = fmaxf(m.x, a2.x); m.y = fmaxf(m.y, a2.y);
      m.z = fmaxf(m.z, a2.z); m.w = fmaxf(m.w, a2.w);
      STEP(); a2 = *p; --rem;
    }
    if (rem > 0) {
      m.x = fmaxf(m.x, a3.x); m.y = fmaxf(m.y, a3.y);
      m.z = fmaxf(m.z, a3.z); m.w = fmaxf(m.w, a3.w);
      STEP(); a3 = *p; --rem;
    }
  }
  m.x = fmaxf(m.x, a0.x); m.y = fmaxf(m.y, a0.y);
  m.z = fmaxf(m.z, a0.z); m.w = fmaxf(m.w, a0.w);
  if (cnt > 1) {
    m.x = fmaxf(m.x, a1.x); m.y = fmaxf(m.y, a1.y);
    m.z = fmaxf(m.z, a1.z); m.w = fmaxf(m.w, a1.w);
  }
  if (cnt > 2) {
    m.x = fmaxf(m.x, a2.x); m.y = fmaxf(m.y, a2.y);
    m.z = fmaxf(m.z, a2.z); m.w = fmaxf(m.w, a2.w);
  }
  if (cnt > 3) {
    m.x = fmaxf(m.x, a3.x); m.y = fmaxf(m.y, a3.y);
    m.z = fmaxf(m.z, a3.z); m.w = fmaxf(m.w, a3.w);
  }
#undef STEP

  vfloat4* o = (vfloat4*)(out + (size_t)cell * RC) + (half << 6) + lane;
  vfloat4 s = {m.x, m.y, m.z, m.w};
  __builtin_nontemporal_store(s, o);  // streaming write: keep L2 for the fm
}

extern "C" void kernel_launch(void* const* d_in, const int* in_sizes, int n_in,
                              void* d_out, int out_size, void* d_ws, size_t ws_size,
                              hipStream_t stream) {
  const float* fm = (const float*)d_in[0];
  const int* rois = (const int*)d_in[1];
  float* out = (float*)d_out;

  roi_pool_kernel<<<CELLS / 2, 256, 0, stream>>>(fm, rois, out);
}